// Round 5
// baseline (169.730 us; speedup 1.0000x reference)
//
#include <hip/hip_runtime.h>
#include <cmath>

#define NN 8192
#define DD 512
#define NSRC 8
#define PSW 8                  // ps partials per row = 8 column groups
#define COFF 100.0f            // fixed softmax offset

typedef __bf16 bf16x8 __attribute__((ext_vector_type(8)));
typedef float  f32x4  __attribute__((ext_vector_type(4)));

__device__ __forceinline__ unsigned short f2bf(float f) {
    unsigned u = __float_as_uint(f);
    u += 0x7fffu + ((u >> 16) & 1u);
    return (unsigned short)(u >> 16);
}

// ---------------------------------------------------------------------------
// Kernel A: blocks 0..127 per-source text sums; blocks 128+ cast fp32->bf16.
// ---------------------------------------------------------------------------
__global__ __launch_bounds__(256) void k_prep(
    const float* __restrict__ img, const float* __restrict__ txt,
    const int* __restrict__ labels,
    unsigned short* __restrict__ imgB, unsigned short* __restrict__ txtB,
    float* __restrict__ Tsum, int* __restrict__ counts)
{
    const int tid = threadIdx.x;
    if (blockIdx.x >= 128) {
        const size_t gid = (size_t)(blockIdx.x - 128) * 256 + tid;
        const size_t half = (size_t)NN * DD / 8;
        const float* src = (gid < half) ? img : txt;
        unsigned short* dst = (gid < half) ? imgB : txtB;
        const size_t off = ((gid < half) ? gid : gid - half) * 8;
        const float4 v0 = *(const float4*)(src + off);
        const float4 v1 = *(const float4*)(src + off + 4);
        union { unsigned short s[8]; uint4 v; } o;
        o.s[0] = f2bf(v0.x); o.s[1] = f2bf(v0.y); o.s[2] = f2bf(v0.z); o.s[3] = f2bf(v0.w);
        o.s[4] = f2bf(v1.x); o.s[5] = f2bf(v1.y); o.s[6] = f2bf(v1.z); o.s[7] = f2bf(v1.w);
        *(uint4*)(dst + off) = o.v;
        return;
    }
    __shared__ float Tacc[NSRC * DD];
    __shared__ int cacc[NSRC];
    const int d0 = 2 * tid;
#pragma unroll
    for (int s = 0; s < NSRC; s++) {
        Tacc[s * DD + d0] = 0.f;
        Tacc[s * DD + d0 + 1] = 0.f;
    }
    if (tid < NSRC) cacc[tid] = 0;
    __syncthreads();

    const int row0 = blockIdx.x * 64;
    if (tid < 64) atomicAdd(&cacc[labels[row0 + tid]], 1);

    for (int j = 0; j < 64; j++) {
        const int lab = labels[row0 + j];
        const float2 v = *(const float2*)(txt + (size_t)(row0 + j) * DD + d0);
        Tacc[lab * DD + d0]     += v.x;
        Tacc[lab * DD + d0 + 1] += v.y;
    }
    __syncthreads();
#pragma unroll
    for (int k = 0; k < NSRC * DD / 256; k++) {
        const int e = k * 256 + tid;
        atomicAdd(&Tsum[e], Tacc[e]);
    }
    if (tid < NSRC) atomicAdd(&counts[tid], cacc[tid]);
}

// ---------------------------------------------------------------------------
// Kernel B (R5): R4's persistent 8-phase GEMM with the lgkmcnt(0)/
// sched_barrier(0) pin REMOVED. ds_reads are compiler-visible C++ loads, so
// hipcc emits fine-grained lgkmcnt(N) between each read and its consuming
// MFMA -> the matrix pipe starts as soon as the first fragments land and
// overlaps the remaining LDS drain (phase = max(LDS,MFMA), was LDS+MFMA).
// Read-issue order matches MFMA consumption order (bf then af, ks-major).
// Barriers / counted-vmcnt schedule / setprio / staging: identical to R4.
// Safety: MFMAs are register-only (barrier position irrelevant); each ds_read
// completes before its consumer MFMA, which precedes the end barrier, which
// precedes any STG overwriting that region (same WAR chain as R4).
// ---------------------------------------------------------------------------
__global__ __launch_bounds__(512, 2) void k_lse_mfma256(
    const unsigned short* __restrict__ imgB, const unsigned short* __restrict__ txtB,
    const float* __restrict__ scale_p, float* __restrict__ ps)
{
    __shared__ uint4 lds[8192];            // 128 KiB
    const float scale = scale_p[0];
    const int tid  = threadIdx.x;
    const int lane = tid & 63;
    const int w    = tid >> 6;
    const int wr   = w >> 2;
    const int wc   = w & 3;
    const int lq   = lane >> 4;
    const int ln   = lane & 15;
    const int c    = blockIdx.x & 7;       // XCD (round-robin dispatch)
    const int l    = blockIdx.x >> 3;
    const int by   = c * 4 + (l >> 3);     // row panel 0..31
    const int bcg  = l & 7;                // column group 0..7
    const int row0    = by * 256;
    const int colBase = bcg * 1024;

    const int st_r  = tid >> 3;
    const int st_kc = (tid & 7) ^ (st_r & 7);
    const int xsw   = ln & 7;

    int rowA[2][4], colB[2][2];
#pragma unroll
    for (int ih = 0; ih < 2; ih++)
#pragma unroll
        for (int ii = 0; ii < 4; ii++)
            rowA[ih][ii] = (wr * 128 + ih * 64 + ii * 16 + ln) * 8;
#pragma unroll
    for (int jh = 0; jh < 2; jh++)
#pragma unroll
        for (int jj = 0; jj < 2; jj++)
            colB[jh][jj] = (wc * 64 + jh * 32 + jj * 16 + ln) * 8;

#define SA(BUF, Q, T)                                                          \
    { const unsigned short* g = imgB + (size_t)(row0 + (Q) * 64 + st_r) * DD   \
          + (((T) & 7) << 6) + (st_kc << 3);                                   \
      __builtin_amdgcn_global_load_lds(                                        \
          (const __attribute__((address_space(1))) void*)g,                    \
          (__attribute__((address_space(3))) void*)                            \
              &lds[(BUF) * 4096 + (Q) * 512 + tid], 16, 0, 0); }
#define SB(BUF, Q, T)                                                          \
    { const unsigned short* g = txtB                                           \
          + (size_t)(colBase + ((((T) >> 3) & 3) << 8) + (Q) * 64 + st_r) * DD \
          + (((T) & 7) << 6) + (st_kc << 3);                                   \
      __builtin_amdgcn_global_load_lds(                                        \
          (const __attribute__((address_space(1))) void*)g,                    \
          (__attribute__((address_space(3))) void*)                            \
              &lds[(BUF) * 4096 + 2048 + (Q) * 512 + tid], 16, 0, 0); }

// Phase: {reads (bf then af, ks-major) | STG} -> barrier -> setprio(1) MFMA
// setprio(0) -> [counted vmcnt] -> barrier. NO lgkmcnt pin, NO sched_barrier:
// the compiler interleaves fine-grained lgkmcnt(N) so MFMA overlaps the drain.
#define PHASE_(BUF, IH, JH, RA, STG, VM)                                       \
    do {                                                                       \
        bf16x8 bf[2][2];                                                       \
        _Pragma("unroll") for (int ks = 0; ks < 2; ks++) {                     \
            _Pragma("unroll") for (int jj = 0; jj < 2; jj++)                   \
                bf[jj][ks] = *reinterpret_cast<const bf16x8*>(                 \
                    &lds[(BUF) * 4096 + 2048 + colB[JH][jj]                    \
                         + (((ks << 2) + lq) ^ xsw)]);                         \
            if (RA) {                                                          \
                _Pragma("unroll") for (int ii = 0; ii < 4; ii++)               \
                    af[ii][ks] = *reinterpret_cast<const bf16x8*>(             \
                        &lds[(BUF) * 4096 + rowA[IH][ii]                       \
                             + (((ks << 2) + lq) ^ xsw)]);                     \
            }                                                                  \
        }                                                                      \
        STG;                                                                   \
        __builtin_amdgcn_s_barrier();                                          \
        __builtin_amdgcn_s_setprio(1);                                         \
        _Pragma("unroll") for (int ks = 0; ks < 2; ks++) {                     \
            _Pragma("unroll") for (int ii = 0; ii < 4; ii++) {                 \
                _Pragma("unroll") for (int jj = 0; jj < 2; jj++) {             \
                    acc[(IH) * 4 + ii][(JH) * 2 + jj] =                        \
                        __builtin_amdgcn_mfma_f32_16x16x32_bf16(               \
                            af[ii][ks], bf[jj][ks],                            \
                            acc[(IH) * 4 + ii][(JH) * 2 + jj], 0, 0, 0);       \
                }                                                              \
            }                                                                  \
        }                                                                      \
        __builtin_amdgcn_s_setprio(0);                                         \
        if (VM) { asm volatile("s_waitcnt vmcnt(2)" ::: "memory"); }           \
        __builtin_amdgcn_s_barrier();                                          \
    } while (0)

    // ---- prologue: tile 0 fully + tile 1 Aq0,Aq2 ----
#pragma unroll
    for (int q = 0; q < 4; q++) SA(0, q, 0);
#pragma unroll
    for (int q = 0; q < 4; q++) SB(0, q, 0);
    SA(1, 0, 1); SA(1, 2, 1);
    asm volatile("s_waitcnt vmcnt(2)" ::: "memory");   // tile 0 landed
    __builtin_amdgcn_s_barrier();

    f32x4 acc[8][4];
    f32x4 s_run[8];
#pragma unroll
    for (int i = 0; i < 8; i++) {
        s_run[i] = (f32x4){0.f, 0.f, 0.f, 0.f};
#pragma unroll
        for (int j = 0; j < 4; j++) acc[i][j] = (f32x4){0.f, 0.f, 0.f, 0.f};
    }
    bf16x8 af[4][2];

#pragma unroll 1
    for (int v0 = 0; v0 < 32; v0 += 2) {
        PHASE_(0, 0, 0, 1,
               SA(1, 1, v0 + 1); SA(1, 3, v0 + 1);
               SB(1, 0, v0 + 1); SB(1, 1, v0 + 1);
               SB(1, 2, v0 + 1); SB(1, 3, v0 + 1), 0);
        PHASE_(0, 0, 1, 0, (void)0, 0);
        PHASE_(0, 1, 0, 1, SA(0, 0, v0 + 2); SA(0, 2, v0 + 2), 0);
        PHASE_(0, 1, 1, 0, (void)0, 1);
        PHASE_(1, 0, 0, 1,
               SA(0, 1, v0 + 2); SA(0, 3, v0 + 2);
               SB(0, 0, v0 + 2); SB(0, 1, v0 + 2);
               SB(0, 2, v0 + 2); SB(0, 3, v0 + 2), 0);
        PHASE_(1, 0, 1, 0, (void)0, 0);
        PHASE_(1, 1, 0, 1, SA(1, 0, v0 + 3); SA(1, 2, v0 + 3), 0);
        PHASE_(1, 1, 1, 0, (void)0, 1);
        if ((v0 & 6) == 6) {
            // ct boundary: register-only exp flush (no barrier, no loads)
#pragma unroll
            for (int i = 0; i < 8; i++) {
#pragma unroll
                for (int rg = 0; rg < 4; rg++) {
                    float es = s_run[i][rg];
#pragma unroll
                    for (int j = 0; j < 4; j++)
                        es += __expf(fmaf(acc[i][j][rg], scale, -COFF));
                    s_run[i][rg] = es;
                }
#pragma unroll
                for (int j = 0; j < 4; j++)
                    acc[i][j] = (f32x4){0.f, 0.f, 0.f, 0.f};
            }
        }
    }

    asm volatile("s_waitcnt vmcnt(0)" ::: "memory");
    __syncthreads();

    // ---- epilogue: reduce s_run across ln, fold 4 wc-waves via LDS ----
    float* fred = (float*)lds;
#pragma unroll
    for (int i = 0; i < 8; i++) {
#pragma unroll
        for (int rg = 0; rg < 4; rg++) {
            float es = s_run[i][rg];
#pragma unroll
            for (int off = 8; off; off >>= 1) es += __shfl_xor(es, off);
            if (ln == 0)
                fred[(wr * 128 + i * 16 + lq * 4 + rg) * 4 + wc] = es;
        }
    }
    __syncthreads();
    if (tid < 256) {
        const float tot = fred[tid * 4] + fred[tid * 4 + 1]
                        + fred[tid * 4 + 2] + fred[tid * 4 + 3];
        ps[(size_t)(row0 + tid) * PSW + bcg] = tot;
    }
#undef SA
#undef SB
#undef PHASE_
}

// ---------------------------------------------------------------------------
// Kernel C: combine partials -> lse, per-row fp32 dot products, reduce.
// ---------------------------------------------------------------------------
__global__ __launch_bounds__(256) void k_finalize(
    const float* __restrict__ img, const float* __restrict__ txt,
    const int* __restrict__ labels, const float* __restrict__ scale_p,
    const float* __restrict__ Tsum, const int* __restrict__ counts,
    const float* __restrict__ ps,
    float* __restrict__ out)
{
    const float scale = scale_p[0];
    const int tid = threadIdx.x;
    const int lane = tid & 63;
    const int wave = tid >> 6;
    const int rowBase = blockIdx.x * 16 + wave * 4;
    float local = 0.f;
#pragma unroll
    for (int it = 0; it < 4; it++) {
        const int i = rowBase + it;
        const int lab = labels[i];
        float ds = 0.f, dt = 0.f;
        const float* ip = img + (size_t)i * DD;
        const float* tp = txt + (size_t)i * DD;
        const float* sp = Tsum + lab * DD;
#pragma unroll
        for (int k = lane; k < DD; k += 64) {
            const float a = ip[k];
            ds = fmaf(a, tp[k], ds);
            dt = fmaf(a, sp[k], dt);
        }
        float es = (lane < PSW) ? ps[(size_t)i * PSW + lane] : 0.f;
#pragma unroll
        for (int off = 32; off; off >>= 1) {
            ds += __shfl_xor(ds, off);
            dt += __shfl_xor(dt, off);
            es += __shfl_xor(es, off);
        }
        if (lane == 0) {
            const float lse = COFF + __logf(es);
            const int cnt = counts[lab] - 1;
            if (cnt > 0) {
                const float row_sum = scale * (dt - ds) - (float)cnt * lse;
                local += row_sum / (float)cnt;
            }
        }
    }
    __shared__ float red[4];
    if (lane == 0) red[wave] = local;
    __syncthreads();
    if (tid == 0) {
        const float t = red[0] + red[1] + red[2] + red[3];
        atomicAdd(out, -t / (float)NN);
    }
}

// ---------------------------------------------------------------------------
extern "C" void kernel_launch(void* const* d_in, const int* in_sizes, int n_in,
                              void* d_out, int out_size, void* d_ws, size_t ws_size,
                              hipStream_t stream)
{
    const float* img     = (const float*)d_in[0];
    const float* txt     = (const float*)d_in[1];
    const float* scale_p = (const float*)d_in[2];
    const int*   labels  = (const int*)d_in[3];
    float* out = (float*)d_out;

    char* ws = (char*)d_ws;
    float* ps    = (float*)(ws);                                  // 256 KB (8192 x 8)
    float* Tsum  = (float*)(ws + (1 << 18));                      // 16 KB
    int*   counts = (int*)(ws + (1 << 18) + NSRC * DD * 4);
    unsigned short* imgB = (unsigned short*)(ws + 2 * 1024 * 1024);   // 8 MB
    unsigned short* txtB = (unsigned short*)(ws + 10 * 1024 * 1024);  // 8 MB

    hipMemsetAsync(ws + (1 << 18), 0, NSRC * DD * 4 + 64, stream);  // Tsum+counts
    hipMemsetAsync(d_out, 0, 4, stream);                            // out

    k_prep<<<128 + (2 * NN * DD / 8) / 256, 256, 0, stream>>>(
        img, txt, labels, imgB, txtB, Tsum, counts);
    k_lse_mfma256<<<256, 512, 0, stream>>>(imgB, txtB, scale_p, ps);
    k_finalize<<<NN / 16, 256, 0, stream>>>(img, txt, labels, scale_p,
                                            Tsum, counts, ps, out);
}